// Round 1
// baseline (480.980 us; speedup 1.0000x reference)
//
#include <hip/hip_runtime.h>
#include <hip/hip_bf16.h>
#include <stdint.h>

typedef unsigned short u16;
typedef unsigned int   u32;

typedef __attribute__((ext_vector_type(8))) short bf16x8;   // 8 bf16 (4 VGPRs)
typedef __attribute__((ext_vector_type(4))) float f32x4;
typedef __attribute__((ext_vector_type(4))) float f4;
typedef __attribute__((ext_vector_type(4))) u16   u16x4;

#define GLOBAL_AS __attribute__((address_space(1)))
#define LDS_AS    __attribute__((address_space(3)))

__device__ __forceinline__ void gload_lds16(const void* gsrc, void* ldst) {
    // async global->LDS, 16B per lane; LDS dest = wave-uniform base + lane*16
    __builtin_amdgcn_global_load_lds((GLOBAL_AS const u32*)gsrc,
                                     (LDS_AS u32*)ldst, 16, 0, 0);
}

__device__ __forceinline__ float b2f(u16 u) {
    union { u32 i; float f; } x; x.i = ((u32)u) << 16; return x.f;
}
__device__ __forceinline__ u16 f2b(float f) {
    u32 u = __builtin_bit_cast(u32, f);
    u = (u + 0x7fff + ((u >> 16) & 1)) >> 16;   // RNE
    return (u16)u;
}

// ---------------------------------------------------------------- converts
__global__ __launch_bounds__(256) void f2bf_kernel(const float* __restrict__ in,
                                                   u16* __restrict__ out, int n4) {
    int i = blockIdx.x * blockDim.x + threadIdx.x;
    if (i >= n4) return;
    f4 v = ((const f4*)in)[i];
    u16x4 o;
    o[0] = f2b(v[0]); o[1] = f2b(v[1]); o[2] = f2b(v[2]); o[3] = f2b(v[3]);
    ((u16x4*)out)[i] = o;
}

// ---------------------------------------------------------------- RoPE (in-place on q,k)
__global__ __launch_bounds__(256) void rope_kernel(u16* __restrict__ q, u16* __restrict__ k,
                                                   const float* __restrict__ fc,
                                                   const float* __restrict__ fs) {
    const int S = 2048;
    int idx = blockIdx.x * blockDim.x + threadIdx.x;  // pair index, 4096*1024 total
    const int p   = idx & 1023;      // pair within row = h*64 + i
    const int row = idx >> 10;       // b*S + s
    const int s   = row & (S - 1);
    const int i   = p & 63;
    const float c = fc[s * 64 + i], sn = fs[s * 64 + i];
    u16* qa = q + ((size_t)row << 11) + p * 2;
    u16* ka = k + ((size_t)row << 11) + p * 2;
    u32 qq = *(const u32*)qa;
    float qr = b2f((u16)(qq & 0xffff)), qi = b2f((u16)(qq >> 16));
    u32 kk = *(const u32*)ka;
    float kr = b2f((u16)(kk & 0xffff)), ki = b2f((u16)(kk >> 16));
    u16 e0 = f2b(qr * c - qi * sn), e1 = f2b(qr * sn + qi * c);
    *(u32*)qa = (u32)e0 | ((u32)e1 << 16);
    e0 = f2b(kr * c - ki * sn); e1 = f2b(kr * sn + ki * c);
    *(u32*)ka = (u32)e0 | ((u32)e1 << 16);
}

// ---------------------------------------------------------------- GEMM  C = A * B^T
// A: MxK bf16 row-major, B: NxK bf16 row-major, C: MxN (bf16 or f32)
// 128x128 tile, BK=32, 4 waves (each 64x64), 16x16x32 MFMA (m97 structure)
template<int OUT_BF16>
__global__ __launch_bounds__(256)
void gemm_bt(const u16* __restrict__ A, const u16* __restrict__ B,
             void* __restrict__ Cptr, int M, int N, int Kdim) {
    __shared__ u16 ldsA[128 * 32];
    __shared__ u16 ldsB[128 * 32];
    const int t = threadIdx.x, l = t & 63, w = t >> 6;
    const int g = l >> 4, r16 = l & 15;
    const int m0 = blockIdx.y * 128, n0 = blockIdx.x * 128;
    const int wr = (w >> 1) * 64, wc = (w & 1) * 64;

    f32x4 acc[4][4];
#pragma unroll
    for (int i = 0; i < 4; i++)
#pragma unroll
        for (int j = 0; j < 4; j++) acc[i][j] = (f32x4){0.f, 0.f, 0.f, 0.f};

    // staging: LDS byte o = instr*4096 + w*1024 + l*16 ; row = o/64, colbyte = o%64
    const int o0 = w * 1024 + l * 16;
    const int r0 = o0 >> 6, c0 = (o0 & 63) >> 1;
    const int o1 = o0 + 4096;
    const int r1 = o1 >> 6, c1 = (o1 & 63) >> 1;
    const u16* a0 = A + (size_t)(m0 + r0) * Kdim + c0;
    const u16* a1 = A + (size_t)(m0 + r1) * Kdim + c1;
    const u16* b0 = B + (size_t)(n0 + r0) * Kdim + c0;
    const u16* b1 = B + (size_t)(n0 + r1) * Kdim + c1;
    char* lA0 = (char*)ldsA + w * 1024;
    char* lA1 = (char*)ldsA + w * 1024 + 4096;
    char* lB0 = (char*)ldsB + w * 1024;
    char* lB1 = (char*)ldsB + w * 1024 + 4096;

    for (int k0 = 0; k0 < Kdim; k0 += 32) {
        __syncthreads();
        gload_lds16(a0, lA0); gload_lds16(a1, lA1);
        gload_lds16(b0, lB0); gload_lds16(b1, lB1);
        a0 += 32; a1 += 32; b0 += 32; b1 += 32;
        __syncthreads();
        bf16x8 af[4], bfr[4];
#pragma unroll
        for (int i = 0; i < 4; i++) {
            af[i]  = *(const bf16x8*)((const char*)ldsA + (wr + i * 16 + r16) * 64 + g * 16);
            bfr[i] = *(const bf16x8*)((const char*)ldsB + (wc + i * 16 + r16) * 64 + g * 16);
        }
#pragma unroll
        for (int mi = 0; mi < 4; mi++)
#pragma unroll
            for (int ni = 0; ni < 4; ni++)
                acc[mi][ni] = __builtin_amdgcn_mfma_f32_16x16x32_bf16(af[mi], bfr[ni],
                                                                      acc[mi][ni], 0, 0, 0);
    }

#pragma unroll
    for (int mi = 0; mi < 4; mi++)
#pragma unroll
        for (int ni = 0; ni < 4; ni++)
#pragma unroll
            for (int r = 0; r < 4; r++) {
                int row = m0 + wr + mi * 16 + g * 4 + r;   // C/D: col=lane&15, row=(lane>>4)*4+reg
                int col = n0 + wc + ni * 16 + r16;
                float v = acc[mi][ni][r];
                if (OUT_BF16) ((u16*)Cptr)[(size_t)row * N + col] = f2b(v);
                else          ((float*)Cptr)[(size_t)row * N + col] = v;
            }
}

// ---------------------------------------------------------------- causal flash attention
// grid.x = q-tile (S/64), grid.y = b*H + h ; 4 waves, each owns 16 q-rows
__global__ __launch_bounds__(256)
void flash_attn(const u16* __restrict__ Q, const u16* __restrict__ Kp,
                const u16* __restrict__ Vp, u16* __restrict__ Op) {
    const int S = 2048, D = 2048;
    __shared__ u16 klds[64 * 128];        // K tile, XOR-swizzled content
    __shared__ u16 vtlds[128 * 72];       // V^T tile, padded 64->72
    __shared__ u16 plds[4][16 * 72];      // per-wave P, padded
    const int t = threadIdx.x, l = t & 63, w = t >> 6;
    const int g = l >> 4, r16 = l & 15;
    const int bh = blockIdx.y, b = bh >> 4, h = bh & 15;
    const int tq = blockIdx.x, q0 = tq * 64;
    const size_t base = ((size_t)(b * S)) * D + h * 128;
    const u16* qp = Q + base;
    const u16* kp = Kp + base;
    const u16* vp = Vp + base;

    bf16x8 qf[4];
#pragma unroll
    for (int ks = 0; ks < 4; ks++)
        qf[ks] = *(const bf16x8*)(qp + (size_t)(q0 + w * 16 + r16) * D + ks * 32 + g * 8);

    f32x4 acc[8];
#pragma unroll
    for (int i = 0; i < 8; i++) acc[i] = (f32x4){0.f, 0.f, 0.f, 0.f};
    float m_run[4], s_run[4];
#pragma unroll
    for (int r = 0; r < 4; r++) { m_run[r] = -3.0e38f; s_run[r] = 0.f; }

    for (int kt = 0; kt <= tq; kt++) {
        const int kv0 = kt * 64;
        __syncthreads();
        // stage K with pre-swizzled global source: stored[o] = K[o/256][(o%256 ^ ((row&7)<<4))/2]
#pragma unroll
        for (int i = 0; i < 4; i++) {
            const int o = i * 4096 + w * 1024 + l * 16;
            const int row = o >> 8;
            const int cb = (o & 255) ^ ((row & 7) << 4);
            gload_lds16(kp + (size_t)(kv0 + row) * D + (cb >> 1),
                        (char*)klds + i * 4096 + w * 1024);
        }
        // stage V transposed: lane l owns kv-row l -> conflict-free b16 column writes
#pragma unroll
        for (int c = 0; c < 4; c++) {
            const int d0 = (c * 4 + w) * 8;
            bf16x8 vv = *(const bf16x8*)(vp + (size_t)(kv0 + l) * D + d0);
#pragma unroll
            for (int j = 0; j < 8; j++)
                vtlds[(d0 + j) * 72 + l] = (u16)vv[j];
        }
        __syncthreads();

        // QK^T
        f32x4 sf[4];
#pragma unroll
        for (int nf = 0; nf < 4; nf++) sf[nf] = (f32x4){0.f, 0.f, 0.f, 0.f};
#pragma unroll
        for (int nf = 0; nf < 4; nf++) {
            const int row = nf * 16 + r16;
            const int rb = row * 256;
#pragma unroll
            for (int ks = 0; ks < 4; ks++) {
                const int cb = (ks * 64 + g * 16) ^ ((row & 7) << 4);
                bf16x8 kf = *(const bf16x8*)((const char*)klds + rb + cb);
                sf[nf] = __builtin_amdgcn_mfma_f32_16x16x32_bf16(qf[ks], kf, sf[nf], 0, 0, 0);
            }
        }
        // scale + causal mask + online softmax
        const float sc = 0.088388347648318447f;
        const bool diag = (kt == tq);
        float mt[4];
#pragma unroll
        for (int r = 0; r < 4; r++) mt[r] = -3.0e38f;
#pragma unroll
        for (int nf = 0; nf < 4; nf++)
#pragma unroll
            for (int r = 0; r < 4; r++) {
                float s = sf[nf][r] * sc;
                if (diag) {
                    int qrow = w * 16 + g * 4 + r;
                    int kcol = nf * 16 + r16;
                    if (kcol > qrow) s = -3.0e38f;
                }
                sf[nf][r] = s;
                mt[r] = fmaxf(mt[r], s);
            }
#pragma unroll
        for (int r = 0; r < 4; r++) {
#pragma unroll
            for (int d = 1; d < 16; d <<= 1)
                mt[r] = fmaxf(mt[r], __shfl_xor(mt[r], d));
        }
        float alpha[4], psum[4];
#pragma unroll
        for (int r = 0; r < 4; r++) {
            float mn = fmaxf(m_run[r], mt[r]);
            alpha[r] = __expf(m_run[r] - mn);
            m_run[r] = mn;
            psum[r] = 0.f;
        }
#pragma unroll
        for (int nf = 0; nf < 4; nf++)
#pragma unroll
            for (int r = 0; r < 4; r++) {
                float p = __expf(sf[nf][r] - m_run[r]);
                psum[r] += p;
                plds[w][(g * 4 + r) * 72 + nf * 16 + r16] = f2b(p);
            }
#pragma unroll
        for (int r = 0; r < 4; r++) {
#pragma unroll
            for (int d = 1; d < 16; d <<= 1)
                psum[r] += __shfl_xor(psum[r], d);
            s_run[r] = s_run[r] * alpha[r] + psum[r];
        }
#pragma unroll
        for (int i = 0; i < 8; i++)
#pragma unroll
            for (int r = 0; r < 4; r++) acc[i][r] *= alpha[r];
        // PV: A = P (from per-wave LDS), B = V^T tile
#pragma unroll
        for (int ks2 = 0; ks2 < 2; ks2++) {
            bf16x8 pf = *(const bf16x8*)(&plds[w][r16 * 72 + ks2 * 32 + g * 8]);
#pragma unroll
            for (int nf = 0; nf < 8; nf++) {
                bf16x8 vf = *(const bf16x8*)(&vtlds[(nf * 16 + r16) * 72 + ks2 * 32 + g * 8]);
                acc[nf] = __builtin_amdgcn_mfma_f32_16x16x32_bf16(pf, vf, acc[nf], 0, 0, 0);
            }
        }
    }
    float inv[4];
#pragma unroll
    for (int r = 0; r < 4; r++) inv[r] = 1.0f / s_run[r];
#pragma unroll
    for (int nf = 0; nf < 8; nf++)
#pragma unroll
        for (int r = 0; r < 4; r++) {
            size_t idx = base + (size_t)(q0 + w * 16 + g * 4 + r) * D + nf * 16 + r16;
            Op[idx] = f2b(acc[nf][r] * inv[r]);
        }
}

// ---------------------------------------------------------------- launch
extern "C" void kernel_launch(void* const* d_in, const int* in_sizes, int n_in,
                              void* d_out, int out_size, void* d_ws, size_t ws_size,
                              hipStream_t stream) {
    const float* x  = (const float*)d_in[0];
    const float* fc = (const float*)d_in[1];
    const float* fs = (const float*)d_in[2];
    const float* wq = (const float*)d_in[3];
    const float* wk = (const float*)d_in[4];
    const float* wv = (const float*)d_in[5];
    const float* wo = (const float*)d_in[6];
    float* out = (float*)d_out;

    const int S = 2048, D = 2048;
    const int M = 2 * S;              // 4096 rows
    const size_t MD = (size_t)M * D;  // 8,388,608
    const size_t DD = (size_t)D * D;  // 4,194,304

    u16* xb  = (u16*)d_ws;
    u16* wqb = xb  + MD;
    u16* wkb = wqb + DD;
    u16* wvb = wkb + DD;
    u16* wob = wvb + DD;
    u16* qb  = wob + DD;
    u16* kb  = qb  + MD;
    u16* vb  = kb  + MD;
    u16* ob  = vb  + MD;

    f2bf_kernel<<<(int)(MD / 1024), 256, 0, stream>>>(x,  xb,  (int)(MD / 4));
    f2bf_kernel<<<(int)(DD / 1024), 256, 0, stream>>>(wq, wqb, (int)(DD / 4));
    f2bf_kernel<<<(int)(DD / 1024), 256, 0, stream>>>(wk, wkb, (int)(DD / 4));
    f2bf_kernel<<<(int)(DD / 1024), 256, 0, stream>>>(wv, wvb, (int)(DD / 4));
    f2bf_kernel<<<(int)(DD / 1024), 256, 0, stream>>>(wo, wob, (int)(DD / 4));

    dim3 ggrid(D / 128, M / 128);  // (16, 32)
    gemm_bt<1><<<ggrid, 256, 0, stream>>>(xb, wqb, qb, M, D, D);
    gemm_bt<1><<<ggrid, 256, 0, stream>>>(xb, wkb, kb, M, D, D);
    gemm_bt<1><<<ggrid, 256, 0, stream>>>(xb, wvb, vb, M, D, D);

    rope_kernel<<<(int)(MD / 2 / 256), 256, 0, stream>>>(qb, kb, fc, fs);

    flash_attn<<<dim3(S / 64, 32), 256, 0, stream>>>(qb, kb, vb, ob);

    gemm_bt<0><<<ggrid, 256, 0, stream>>>(ob, wob, out, M, D, D);
}

// Round 2
// 449.742 us; speedup vs baseline: 1.0695x; 1.0695x over previous
//
#include <hip/hip_runtime.h>
#include <hip/hip_bf16.h>
#include <stdint.h>

typedef unsigned short u16;
typedef unsigned int   u32;

typedef __attribute__((ext_vector_type(8))) short bf16x8;   // 8 bf16 (4 VGPRs)
typedef __attribute__((ext_vector_type(4))) float f32x4;
typedef __attribute__((ext_vector_type(4))) float f4;
typedef __attribute__((ext_vector_type(4))) u16   u16x4;

#define GLOBAL_AS __attribute__((address_space(1)))
#define LDS_AS    __attribute__((address_space(3)))

__device__ __forceinline__ void gload_lds16(const void* gsrc, void* ldst) {
    // async global->LDS, 16B per lane; LDS dest = wave-uniform base + lane*16
    __builtin_amdgcn_global_load_lds((GLOBAL_AS const u32*)gsrc,
                                     (LDS_AS u32*)ldst, 16, 0, 0);
}

__device__ __forceinline__ float b2f(u16 u) {
    union { u32 i; float f; } x; x.i = ((u32)u) << 16; return x.f;
}
__device__ __forceinline__ u16 f2b(float f) {
    u32 u = __builtin_bit_cast(u32, f);
    u = (u + 0x7fff + ((u >> 16) & 1)) >> 16;   // RNE
    return (u16)u;
}

// ---------------------------------------------------------------- converts
__global__ __launch_bounds__(256) void f2bf_kernel(const float* __restrict__ in,
                                                   u16* __restrict__ out, int n4) {
    int i = blockIdx.x * blockDim.x + threadIdx.x;
    if (i >= n4) return;
    f4 v = ((const f4*)in)[i];
    u16x4 o;
    o[0] = f2b(v[0]); o[1] = f2b(v[1]); o[2] = f2b(v[2]); o[3] = f2b(v[3]);
    ((u16x4*)out)[i] = o;
}

// ---------------------------------------------------------------- RoPE (in-place on q,k)
__global__ __launch_bounds__(256) void rope_kernel(u16* __restrict__ q, u16* __restrict__ k,
                                                   const float* __restrict__ fc,
                                                   const float* __restrict__ fs) {
    const int S = 2048;
    int idx = blockIdx.x * blockDim.x + threadIdx.x;  // pair index
    const int p   = idx & 1023;      // pair within row = h*64 + i
    const int row = idx >> 10;       // b*S + s
    const int s   = row & (S - 1);
    const int i   = p & 63;
    const float c = fc[s * 64 + i], sn = fs[s * 64 + i];
    u16* qa = q + ((size_t)row << 11) + p * 2;
    u16* ka = k + ((size_t)row << 11) + p * 2;
    u32 qq = *(const u32*)qa;
    float qr = b2f((u16)(qq & 0xffff)), qi = b2f((u16)(qq >> 16));
    u32 kk = *(const u32*)ka;
    float kr = b2f((u16)(kk & 0xffff)), ki = b2f((u16)(kk >> 16));
    u16 e0 = f2b(qr * c - qi * sn), e1 = f2b(qr * sn + qi * c);
    *(u32*)qa = (u32)e0 | ((u32)e1 << 16);
    e0 = f2b(kr * c - ki * sn); e1 = f2b(kr * sn + ki * c);
    *(u32*)ka = (u32)e0 | ((u32)e1 << 16);
}

// ---------------------------------------------------------------- GEMM  C = A * B^T
// A: MxK bf16 row-major, B: NxK bf16 row-major, C: MxN (bf16 or f32)
// 128x128 tile, BK=32, 4 waves (each 64x64), 16x16x32 MFMA (m97 structure)
template<int OUT_BF16>
__global__ __launch_bounds__(256)
void gemm_bt(const u16* __restrict__ A, const u16* __restrict__ B,
             void* __restrict__ Cptr, int M, int N, int Kdim) {
    __shared__ u16 ldsA[128 * 32];
    __shared__ u16 ldsB[128 * 32];
    const int t = threadIdx.x, l = t & 63, w = t >> 6;
    const int g = l >> 4, r16 = l & 15;
    const int m0 = blockIdx.y * 128, n0 = blockIdx.x * 128;
    const int wr = (w >> 1) * 64, wc = (w & 1) * 64;

    f32x4 acc[4][4];
#pragma unroll
    for (int i = 0; i < 4; i++)
#pragma unroll
        for (int j = 0; j < 4; j++) acc[i][j] = (f32x4){0.f, 0.f, 0.f, 0.f};

    const int o0 = w * 1024 + l * 16;
    const int r0 = o0 >> 6, c0 = (o0 & 63) >> 1;
    const int o1 = o0 + 4096;
    const int r1 = o1 >> 6, c1 = (o1 & 63) >> 1;
    const u16* a0 = A + (size_t)(m0 + r0) * Kdim + c0;
    const u16* a1 = A + (size_t)(m0 + r1) * Kdim + c1;
    const u16* b0 = B + (size_t)(n0 + r0) * Kdim + c0;
    const u16* b1 = B + (size_t)(n0 + r1) * Kdim + c1;
    char* lA0 = (char*)ldsA + w * 1024;
    char* lA1 = (char*)ldsA + w * 1024 + 4096;
    char* lB0 = (char*)ldsB + w * 1024;
    char* lB1 = (char*)ldsB + w * 1024 + 4096;

    for (int k0 = 0; k0 < Kdim; k0 += 32) {
        __syncthreads();
        gload_lds16(a0, lA0); gload_lds16(a1, lA1);
        gload_lds16(b0, lB0); gload_lds16(b1, lB1);
        a0 += 32; a1 += 32; b0 += 32; b1 += 32;
        __syncthreads();
        bf16x8 af[4], bfr[4];
#pragma unroll
        for (int i = 0; i < 4; i++) {
            af[i]  = *(const bf16x8*)((const char*)ldsA + (wr + i * 16 + r16) * 64 + g * 16);
            bfr[i] = *(const bf16x8*)((const char*)ldsB + (wc + i * 16 + r16) * 64 + g * 16);
        }
#pragma unroll
        for (int mi = 0; mi < 4; mi++)
#pragma unroll
            for (int ni = 0; ni < 4; ni++)
                acc[mi][ni] = __builtin_amdgcn_mfma_f32_16x16x32_bf16(af[mi], bfr[ni],
                                                                      acc[mi][ni], 0, 0, 0);
    }

#pragma unroll
    for (int mi = 0; mi < 4; mi++)
#pragma unroll
        for (int ni = 0; ni < 4; ni++)
#pragma unroll
            for (int r = 0; r < 4; r++) {
                int row = m0 + wr + mi * 16 + g * 4 + r;
                int col = n0 + wc + ni * 16 + r16;
                float v = acc[mi][ni][r];
                if (OUT_BF16) ((u16*)Cptr)[(size_t)row * N + col] = f2b(v);
                else          ((float*)Cptr)[(size_t)row * N + col] = v;
            }
}

// ---------------------------------------------------------------- causal flash attention v2
// QBLK=128 (4 waves x 32 rows), KVBLK=64, double-buffered K (gload_lds, swizzled)
// and V^T (reg-staged, T14 issue-early/write-late), one barrier per kv-tile.
// grid (16, 32); tq remapped so CU block pairs have complementary causal work.
__global__ __launch_bounds__(256)
void flash_attn(const u16* __restrict__ Q, const u16* __restrict__ Kp,
                const u16* __restrict__ Vp, u16* __restrict__ Op) {
    const int S = 2048, D = 2048;
    __shared__ u16 klds[2][64 * 128];     // swizzled: byte_in_row ^= ((row&7)<<4)
    __shared__ u16 vtlds[2][128 * 72];    // V^T: [d][kv], kv padded 64->72
    __shared__ u16 plds[4][16 * 72];      // per-wave P (one m-frag at a time)
    const int t = threadIdx.x, l = t & 63, w = t >> 6;
    const int g = l >> 4, r16 = l & 15;
    const int bh = blockIdx.y, b = bh >> 4, h = bh & 15;
    const int tq = (bh < 16) ? blockIdx.x : (15 - blockIdx.x);   // balance pairing
    const int q0 = tq * 128;
    const size_t base = ((size_t)(b * S)) * D + h * 128;
    const u16* qp = Q + base;
    const u16* kp = Kp + base;
    const u16* vp = Vp + base;

    // Q fragments: wave rows q0 + w*32 + mf*16 + r16
    bf16x8 qf[2][4];
#pragma unroll
    for (int mf = 0; mf < 2; mf++)
#pragma unroll
        for (int ks = 0; ks < 4; ks++)
            qf[mf][ks] = *(const bf16x8*)(qp + (size_t)(q0 + w * 32 + mf * 16 + r16) * D
                                          + ks * 32 + g * 8);

    f32x4 acc[2][8];
#pragma unroll
    for (int mf = 0; mf < 2; mf++)
#pragma unroll
        for (int i = 0; i < 8; i++) acc[mf][i] = (f32x4){0.f, 0.f, 0.f, 0.f};
    float m_run[2][4], s_run[2][4];
#pragma unroll
    for (int mf = 0; mf < 2; mf++)
#pragma unroll
        for (int r = 0; r < 4; r++) { m_run[mf][r] = -3.0e38f; s_run[mf][r] = 0.f; }

    const int nkt = 2 * tq + 2;

    auto stageK = [&](int bi, int kv0) {
#pragma unroll
        for (int i = 0; i < 4; i++) {
            const int o = i * 4096 + w * 1024 + l * 16;
            const int row = o >> 8;
            const int cb = (o & 255) ^ ((row & 7) << 4);
            gload_lds16(kp + (size_t)(kv0 + row) * D + (cb >> 1),
                        (char*)klds[bi] + i * 4096 + w * 1024);
        }
    };
    bf16x8 vv[4];
    auto loadV = [&](int kv0) {
#pragma unroll
        for (int c = 0; c < 4; c++)
            vv[c] = *(const bf16x8*)(vp + (size_t)(kv0 + l) * D + (w * 32 + c * 8));
    };
    auto writeVT = [&](int bi) {
#pragma unroll
        for (int c = 0; c < 4; c++) {
            const int d0 = w * 32 + c * 8;
#pragma unroll
            for (int j = 0; j < 8; j++)
                vtlds[bi][(d0 + j) * 72 + l] = (u16)vv[c][j];
        }
    };

    // prologue: stage tile 0
    stageK(0, 0);
    loadV(0);
    writeVT(0);
    __syncthreads();

    int cur = 0;
    for (int kt = 0; kt < nkt; ++kt) {
        const int kv0 = kt * 64;
        const int nxt = cur ^ 1;
        const bool more = (kt + 1 < nkt);
        if (more) { stageK(nxt, kv0 + 64); loadV(kv0 + 64); }   // issue early

        // ---- QK^T from klds[cur]
        f32x4 sf[2][4];
#pragma unroll
        for (int mf = 0; mf < 2; mf++)
#pragma unroll
            for (int nf = 0; nf < 4; nf++) sf[mf][nf] = (f32x4){0.f, 0.f, 0.f, 0.f};
#pragma unroll
        for (int nf = 0; nf < 4; nf++) {
            const int row = nf * 16 + r16;
            const int rb = row * 256;
            bf16x8 kf[4];
#pragma unroll
            for (int ks = 0; ks < 4; ks++) {
                const int cb = (ks * 64 + g * 16) ^ ((row & 7) << 4);
                kf[ks] = *(const bf16x8*)((const char*)klds[cur] + rb + cb);
            }
#pragma unroll
            for (int mf = 0; mf < 2; mf++)
#pragma unroll
                for (int ks = 0; ks < 4; ks++)
                    sf[mf][nf] = __builtin_amdgcn_mfma_f32_16x16x32_bf16(qf[mf][ks], kf[ks],
                                                                         sf[mf][nf], 0, 0, 0);
        }

        const float sc = 0.088388347648318447f;
        const bool diag = (kt >= 2 * tq);
#pragma unroll
        for (int mf = 0; mf < 2; mf++) {
            float mt[4];
#pragma unroll
            for (int r = 0; r < 4; r++) mt[r] = -3.0e38f;
#pragma unroll
            for (int nf = 0; nf < 4; nf++)
#pragma unroll
                for (int r = 0; r < 4; r++) {
                    float s = sf[mf][nf][r] * sc;
                    if (diag) {
                        int qrow = q0 + w * 32 + mf * 16 + g * 4 + r;
                        int kcol = kv0 + nf * 16 + r16;
                        if (kcol > qrow) s = -3.0e38f;
                    }
                    sf[mf][nf][r] = s;
                    mt[r] = fmaxf(mt[r], s);
                }
#pragma unroll
            for (int r = 0; r < 4; r++) {
#pragma unroll
                for (int d = 1; d < 16; d <<= 1)
                    mt[r] = fmaxf(mt[r], __shfl_xor(mt[r], d));
            }
            float alpha[4], psum[4];
#pragma unroll
            for (int r = 0; r < 4; r++) {
                float mn = fmaxf(m_run[mf][r], mt[r]);
                alpha[r] = __expf(m_run[mf][r] - mn);
                m_run[mf][r] = mn;
                psum[r] = 0.f;
            }
#pragma unroll
            for (int nf = 0; nf < 4; nf++)
#pragma unroll
                for (int r = 0; r < 4; r++) {
                    float p = __expf(sf[mf][nf][r] - m_run[mf][r]);
                    psum[r] += p;
                    plds[w][(g * 4 + r) * 72 + nf * 16 + r16] = f2b(p);
                }
#pragma unroll
            for (int r = 0; r < 4; r++) {
#pragma unroll
                for (int d = 1; d < 16; d <<= 1)
                    psum[r] += __shfl_xor(psum[r], d);
                s_run[mf][r] = s_run[mf][r] * alpha[r] + psum[r];
            }
#pragma unroll
            for (int i = 0; i < 8; i++)
#pragma unroll
                for (int r = 0; r < 4; r++) acc[mf][i][r] *= alpha[r];
            // ---- PV for this m-frag
#pragma unroll
            for (int ks2 = 0; ks2 < 2; ks2++) {
                bf16x8 pf = *(const bf16x8*)(&plds[w][r16 * 72 + ks2 * 32 + g * 8]);
#pragma unroll
                for (int nf8 = 0; nf8 < 8; nf8++) {
                    bf16x8 vf = *(const bf16x8*)(&vtlds[cur][(nf8 * 16 + r16) * 72
                                                             + ks2 * 32 + g * 8]);
                    acc[mf][nf8] = __builtin_amdgcn_mfma_f32_16x16x32_bf16(pf, vf,
                                                                           acc[mf][nf8], 0, 0, 0);
                }
            }
        }

        if (more) writeVT(nxt);   // write late (vmcnt drains here, hidden under compute)
        __syncthreads();          // single barrier per kv-tile
        cur = nxt;
    }

#pragma unroll
    for (int mf = 0; mf < 2; mf++) {
        float inv[4];
#pragma unroll
        for (int r = 0; r < 4; r++) inv[r] = 1.0f / s_run[mf][r];
#pragma unroll
        for (int nf8 = 0; nf8 < 8; nf8++)
#pragma unroll
            for (int r = 0; r < 4; r++) {
                size_t idx = base + (size_t)(q0 + w * 32 + mf * 16 + g * 4 + r) * D
                             + nf8 * 16 + r16;
                Op[idx] = f2b(acc[mf][nf8][r] * inv[r]);
            }
    }
}

// ---------------------------------------------------------------- launch
extern "C" void kernel_launch(void* const* d_in, const int* in_sizes, int n_in,
                              void* d_out, int out_size, void* d_ws, size_t ws_size,
                              hipStream_t stream) {
    const float* x  = (const float*)d_in[0];
    const float* fc = (const float*)d_in[1];
    const float* fs = (const float*)d_in[2];
    const float* wq = (const float*)d_in[3];
    const float* wk = (const float*)d_in[4];
    const float* wv = (const float*)d_in[5];
    const float* wo = (const float*)d_in[6];
    float* out = (float*)d_out;

    const int S = 2048, D = 2048;
    const int M = 2 * S;              // 4096 rows
    const size_t MD = (size_t)M * D;  // 8,388,608
    const size_t DD = (size_t)D * D;  // 4,194,304

    u16* xb  = (u16*)d_ws;
    u16* wqb = xb  + MD;
    u16* wkb = wqb + DD;
    u16* wvb = wkb + DD;
    u16* wob = wvb + DD;
    u16* qb  = wob + DD;
    u16* kb  = qb  + MD;
    u16* vb  = kb  + MD;
    u16* ob  = vb  + MD;

    f2bf_kernel<<<(int)(MD / 1024), 256, 0, stream>>>(x,  xb,  (int)(MD / 4));
    f2bf_kernel<<<(int)(DD / 1024), 256, 0, stream>>>(wq, wqb, (int)(DD / 4));
    f2bf_kernel<<<(int)(DD / 1024), 256, 0, stream>>>(wk, wkb, (int)(DD / 4));
    f2bf_kernel<<<(int)(DD / 1024), 256, 0, stream>>>(wv, wvb, (int)(DD / 4));
    f2bf_kernel<<<(int)(DD / 1024), 256, 0, stream>>>(wo, wob, (int)(DD / 4));

    dim3 ggrid(D / 128, M / 128);  // (16, 32)
    gemm_bt<1><<<ggrid, 256, 0, stream>>>(xb, wqb, qb, M, D, D);
    gemm_bt<1><<<ggrid, 256, 0, stream>>>(xb, wkb, kb, M, D, D);
    gemm_bt<1><<<ggrid, 256, 0, stream>>>(xb, wvb, vb, M, D, D);

    rope_kernel<<<(int)(MD / 2 / 256), 256, 0, stream>>>(qb, kb, fc, fs);

    flash_attn<<<dim3(S / 128, 32), 256, 0, stream>>>(qb, kb, vb, ob);

    gemm_bt<0><<<ggrid, 256, 0, stream>>>(ob, wob, out, M, D, D);
}

// Round 3
// 410.374 us; speedup vs baseline: 1.1721x; 1.0959x over previous
//
#include <hip/hip_runtime.h>
#include <hip/hip_bf16.h>
#include <stdint.h>

typedef unsigned short u16;
typedef unsigned int   u32;

typedef __attribute__((ext_vector_type(8))) short bf16x8;   // 8 bf16 (4 VGPRs)
typedef __attribute__((ext_vector_type(4))) float f32x4;
typedef __attribute__((ext_vector_type(4))) float f4;
typedef __attribute__((ext_vector_type(4))) u16   u16x4;

#define GLOBAL_AS __attribute__((address_space(1)))
#define LDS_AS    __attribute__((address_space(3)))

// 1/sqrt(128) * log2(e)  -- folded into Q so softmax exp is a bare v_exp_f32
#define QSCALE (0.088388347648318447f * 1.4426950408889634f)

__device__ __forceinline__ void gload_lds16(const void* gsrc, void* ldst) {
    __builtin_amdgcn_global_load_lds((GLOBAL_AS const u32*)gsrc,
                                     (LDS_AS u32*)ldst, 16, 0, 0);
}

__device__ __forceinline__ float b2f(u16 u) {
    union { u32 i; float f; } x; x.i = ((u32)u) << 16; return x.f;
}
__device__ __forceinline__ u16 f2b(float f) {
    u32 u = __builtin_bit_cast(u32, f);
    u = (u + 0x7fff + ((u >> 16) & 1)) >> 16;   // RNE
    return (u16)u;
}

// ---------------------------------------------------------------- converts
__global__ __launch_bounds__(256) void f2bf_kernel(const float* __restrict__ in,
                                                   u16* __restrict__ out, int n4) {
    int i = blockIdx.x * blockDim.x + threadIdx.x;
    if (i >= n4) return;
    f4 v = ((const f4*)in)[i];
    u16x4 o;
    o[0] = f2b(v[0]); o[1] = f2b(v[1]); o[2] = f2b(v[2]); o[3] = f2b(v[3]);
    ((u16x4*)out)[i] = o;
}

// ---------------------------------------------------------------- RoPE (in-place on q,k)
__global__ __launch_bounds__(256) void rope_kernel(u16* __restrict__ q, u16* __restrict__ k,
                                                   const float* __restrict__ fc,
                                                   const float* __restrict__ fs) {
    const int S = 2048;
    int idx = blockIdx.x * blockDim.x + threadIdx.x;  // pair index
    const int p   = idx & 1023;      // pair within row = h*64 + i
    const int row = idx >> 10;       // b*S + s
    const int s   = row & (S - 1);
    const int i   = p & 63;
    const float c = fc[s * 64 + i], sn = fs[s * 64 + i];
    u16* qa = q + ((size_t)row << 11) + p * 2;
    u16* ka = k + ((size_t)row << 11) + p * 2;
    u32 qq = *(const u32*)qa;
    float qr = b2f((u16)(qq & 0xffff)), qi = b2f((u16)(qq >> 16));
    u32 kk = *(const u32*)ka;
    float kr = b2f((u16)(kk & 0xffff)), ki = b2f((u16)(kk >> 16));
    u16 e0 = f2b(qr * c - qi * sn), e1 = f2b(qr * sn + qi * c);
    *(u32*)qa = (u32)e0 | ((u32)e1 << 16);
    e0 = f2b(kr * c - ki * sn); e1 = f2b(kr * sn + ki * c);
    *(u32*)ka = (u32)e0 | ((u32)e1 << 16);
}

// ---------------------------------------------------------------- GEMM  C = A * B^T
// OUT_MODE: 0 = f32, 1 = bf16, 2 = bf16 scaled by QSCALE
template<int OUT_MODE>
__global__ __launch_bounds__(256)
void gemm_bt(const u16* __restrict__ A, const u16* __restrict__ B,
             void* __restrict__ Cptr, int M, int N, int Kdim) {
    __shared__ u16 ldsA[128 * 32];
    __shared__ u16 ldsB[128 * 32];
    const int t = threadIdx.x, l = t & 63, w = t >> 6;
    const int g = l >> 4, r16 = l & 15;
    const int m0 = blockIdx.y * 128, n0 = blockIdx.x * 128;
    const int wr = (w >> 1) * 64, wc = (w & 1) * 64;

    f32x4 acc[4][4];
#pragma unroll
    for (int i = 0; i < 4; i++)
#pragma unroll
        for (int j = 0; j < 4; j++) acc[i][j] = (f32x4){0.f, 0.f, 0.f, 0.f};

    const int o0 = w * 1024 + l * 16;
    const int r0 = o0 >> 6, c0 = (o0 & 63) >> 1;
    const int o1 = o0 + 4096;
    const int r1 = o1 >> 6, c1 = (o1 & 63) >> 1;
    const u16* a0 = A + (size_t)(m0 + r0) * Kdim + c0;
    const u16* a1 = A + (size_t)(m0 + r1) * Kdim + c1;
    const u16* b0 = B + (size_t)(n0 + r0) * Kdim + c0;
    const u16* b1 = B + (size_t)(n0 + r1) * Kdim + c1;
    char* lA0 = (char*)ldsA + w * 1024;
    char* lA1 = (char*)ldsA + w * 1024 + 4096;
    char* lB0 = (char*)ldsB + w * 1024;
    char* lB1 = (char*)ldsB + w * 1024 + 4096;

    for (int k0 = 0; k0 < Kdim; k0 += 32) {
        __syncthreads();
        gload_lds16(a0, lA0); gload_lds16(a1, lA1);
        gload_lds16(b0, lB0); gload_lds16(b1, lB1);
        a0 += 32; a1 += 32; b0 += 32; b1 += 32;
        __syncthreads();
        bf16x8 af[4], bfr[4];
#pragma unroll
        for (int i = 0; i < 4; i++) {
            af[i]  = *(const bf16x8*)((const char*)ldsA + (wr + i * 16 + r16) * 64 + g * 16);
            bfr[i] = *(const bf16x8*)((const char*)ldsB + (wc + i * 16 + r16) * 64 + g * 16);
        }
#pragma unroll
        for (int mi = 0; mi < 4; mi++)
#pragma unroll
            for (int ni = 0; ni < 4; ni++)
                acc[mi][ni] = __builtin_amdgcn_mfma_f32_16x16x32_bf16(af[mi], bfr[ni],
                                                                      acc[mi][ni], 0, 0, 0);
    }

#pragma unroll
    for (int mi = 0; mi < 4; mi++)
#pragma unroll
        for (int ni = 0; ni < 4; ni++)
#pragma unroll
            for (int r = 0; r < 4; r++) {
                int row = m0 + wr + mi * 16 + g * 4 + r;
                int col = n0 + wc + ni * 16 + r16;
                float v = acc[mi][ni][r];
                if (OUT_MODE == 0)      ((float*)Cptr)[(size_t)row * N + col] = v;
                else if (OUT_MODE == 1) ((u16*)Cptr)[(size_t)row * N + col] = f2b(v);
                else                    ((u16*)Cptr)[(size_t)row * N + col] = f2b(v * QSCALE);
            }
}

// ---------------------------------------------------------------- causal flash attention v3
// QBLK=256 (8 waves x 32 rows), KVBLK=128. K double-buffered (gload_lds, XOR-swizzled);
// V^T single-buffered reg-staged (issue-early / write-late). Two barriers per kv-tile.
// grid (8, 32) = 256 blocks = 1/CU -> wall = deepest block (16 iters), no stacking.
// Q is pre-scaled by 1/sqrt(hd)*log2e so softmax uses bare exp2.
__global__ __launch_bounds__(512, 2)
void flash_attn(const u16* __restrict__ Q, const u16* __restrict__ Kp,
                const u16* __restrict__ Vp, u16* __restrict__ Op) {
    const int S = 2048, D = 2048;
    __shared__ u16 klds[2][128 * 128];    // 128 rows x 256B, swizzled byte^=((row&7)<<4)
    __shared__ u16 vtlds[128 * 136];      // V^T [d][kv], kv padded 128->136
    __shared__ u16 plds[8][16 * 136];     // per-wave P (one 16-row m-frag at a time)
    const int t = threadIdx.x, l = t & 63, w = t >> 6;   // w in 0..7
    const int g = l >> 4, r16 = l & 15;
    const int bh = blockIdx.y, b = bh >> 4, h = bh & 15;
    const int tq = blockIdx.x;            // 0..7
    const int q0 = tq * 256;
    const size_t base = ((size_t)(b * S)) * D + h * 128;
    const u16* qp = Q + base;
    const u16* kp = Kp + base;
    const u16* vp = Vp + base;
    const int nkt = 2 * tq + 2;

    // Q fragments: rows q0 + w*32 + mf*16 + r16 (Q already scaled)
    bf16x8 qf[2][4];
#pragma unroll
    for (int mf = 0; mf < 2; mf++)
#pragma unroll
        for (int ks = 0; ks < 4; ks++)
            qf[mf][ks] = *(const bf16x8*)(qp + (size_t)(q0 + w * 32 + mf * 16 + r16) * D
                                          + ks * 32 + g * 8);

    f32x4 acc[2][8];
#pragma unroll
    for (int mf = 0; mf < 2; mf++)
#pragma unroll
        for (int i = 0; i < 8; i++) acc[mf][i] = (f32x4){0.f, 0.f, 0.f, 0.f};
    float m_run[2][4], s_run[2][4];
#pragma unroll
    for (int mf = 0; mf < 2; mf++)
#pragma unroll
        for (int r = 0; r < 4; r++) { m_run[mf][r] = -3.0e38f; s_run[mf][r] = 0.f; }

    auto stageK = [&](int bi, int kv0) {
#pragma unroll
        for (int i = 0; i < 4; i++) {
            const int o = (w * 4 + i) * 1024 + l * 16;     // 0..32767
            const int row = o >> 8;
            const int cb = (o & 255) ^ ((row & 7) << 4);
            gload_lds16(kp + (size_t)(kv0 + row) * D + (cb >> 1),
                        (char*)klds[bi] + (w * 4 + i) * 1024);
        }
    };
    bf16x8 vv[2][2];
    auto loadV = [&](int kv0) {
#pragma unroll
        for (int c = 0; c < 2; c++)
#pragma unroll
            for (int kh = 0; kh < 2; kh++)
                vv[c][kh] = *(const bf16x8*)(vp + (size_t)(kv0 + kh * 64 + l) * D
                                             + (w * 16 + c * 8));
    };
    auto writeVT = [&]() {
#pragma unroll
        for (int c = 0; c < 2; c++)
#pragma unroll
            for (int kh = 0; kh < 2; kh++) {
                const int d0 = w * 16 + c * 8;
#pragma unroll
                for (int j = 0; j < 8; j++)
                    vtlds[(d0 + j) * 136 + kh * 64 + l] = (u16)vv[c][kh][j];
            }
    };

    // prologue: stage tile 0
    stageK(0, 0);
    loadV(0);
    __syncthreads();
    writeVT();
    __syncthreads();

    int cur = 0;
    for (int kt = 0; kt < nkt; ++kt) {
        const int kv0 = kt * 128;
        const bool more = (kt + 1 < nkt);
        if (more) { stageK(cur ^ 1, kv0 + 128); loadV(kv0 + 128); }   // issue early

        const bool active = (kv0 <= q0 + w * 32 + 31);   // wave has unmasked rows
        if (active) {
            // ---- QK^T from klds[cur]
            f32x4 sf[2][8];
#pragma unroll
            for (int mf = 0; mf < 2; mf++)
#pragma unroll
                for (int nf = 0; nf < 8; nf++) sf[mf][nf] = (f32x4){0.f, 0.f, 0.f, 0.f};
#pragma unroll
            for (int nf = 0; nf < 8; nf++) {
                const int row = nf * 16 + r16;
                const int rb = row * 256;
                bf16x8 kf[4];
#pragma unroll
                for (int ks = 0; ks < 4; ks++) {
                    const int cb = (ks * 64 + g * 16) ^ ((row & 7) << 4);
                    kf[ks] = *(const bf16x8*)((const char*)klds[cur] + rb + cb);
                }
#pragma unroll
                for (int mf = 0; mf < 2; mf++)
#pragma unroll
                    for (int ks = 0; ks < 4; ks++)
                        sf[mf][nf] = __builtin_amdgcn_mfma_f32_16x16x32_bf16(qf[mf][ks], kf[ks],
                                                                             sf[mf][nf], 0, 0, 0);
            }

            const bool diag = (kt >= 2 * tq);
#pragma unroll
            for (int mf = 0; mf < 2; mf++) {
                float mt[4];
#pragma unroll
                for (int r = 0; r < 4; r++) mt[r] = -3.0e38f;
#pragma unroll
                for (int nf = 0; nf < 8; nf++)
#pragma unroll
                    for (int r = 0; r < 4; r++) {
                        float s = sf[mf][nf][r];
                        if (diag) {
                            int qrow = q0 + w * 32 + mf * 16 + g * 4 + r;
                            int kcol = kv0 + nf * 16 + r16;
                            if (kcol > qrow) s = -3.0e38f;
                        }
                        sf[mf][nf][r] = s;
                        mt[r] = fmaxf(mt[r], s);
                    }
#pragma unroll
                for (int r = 0; r < 4; r++) {
#pragma unroll
                    for (int d = 1; d < 16; d <<= 1)
                        mt[r] = fmaxf(mt[r], __shfl_xor(mt[r], d));
                }
                // T13 defer-max: rescale only if any row's max grew by > 8 (log2 domain)
                int grow = (mt[0] > m_run[mf][0] + 8.f) | (mt[1] > m_run[mf][1] + 8.f) |
                           (mt[2] > m_run[mf][2] + 8.f) | (mt[3] > m_run[mf][3] + 8.f);
                if (__any(grow)) {
#pragma unroll
                    for (int r = 0; r < 4; r++) {
                        float mn = fmaxf(m_run[mf][r], mt[r]);
                        float alpha = exp2f(m_run[mf][r] - mn);
                        m_run[mf][r] = mn;
                        s_run[mf][r] *= alpha;
#pragma unroll
                        for (int i = 0; i < 8; i++) acc[mf][i][r] *= alpha;
                    }
                }
                float psum[4];
#pragma unroll
                for (int r = 0; r < 4; r++) psum[r] = 0.f;
#pragma unroll
                for (int nf = 0; nf < 8; nf++)
#pragma unroll
                    for (int r = 0; r < 4; r++) {
                        float p = exp2f(sf[mf][nf][r] - m_run[mf][r]);
                        psum[r] += p;
                        plds[w][(g * 4 + r) * 136 + nf * 16 + r16] = f2b(p);
                    }
#pragma unroll
                for (int r = 0; r < 4; r++) {
#pragma unroll
                    for (int d = 1; d < 16; d <<= 1)
                        psum[r] += __shfl_xor(psum[r], d);
                    s_run[mf][r] += psum[r];
                }
                // ---- PV for this m-frag (V^T single buffer, K-dim = 128)
                __builtin_amdgcn_s_setprio(1);
#pragma unroll
                for (int ks2 = 0; ks2 < 4; ks2++) {
                    bf16x8 pf = *(const bf16x8*)(&plds[w][r16 * 136 + ks2 * 32 + g * 8]);
#pragma unroll
                    for (int nf8 = 0; nf8 < 8; nf8++) {
                        bf16x8 vf = *(const bf16x8*)(&vtlds[(nf8 * 16 + r16) * 136
                                                             + ks2 * 32 + g * 8]);
                        acc[mf][nf8] = __builtin_amdgcn_mfma_f32_16x16x32_bf16(pf, vf,
                                                                               acc[mf][nf8],
                                                                               0, 0, 0);
                    }
                }
                __builtin_amdgcn_s_setprio(0);
            }
        }

        __syncthreads();          // all PV reads of V^T done; stage vmcnt drained
        if (more) writeVT();      // overwrite V^T with tile kt+1
        __syncthreads();          // V^T(kt+1) + klds[cur^1] ready
        cur ^= 1;
    }

#pragma unroll
    for (int mf = 0; mf < 2; mf++) {
        float inv[4];
#pragma unroll
        for (int r = 0; r < 4; r++) inv[r] = 1.0f / s_run[mf][r];
#pragma unroll
        for (int nf8 = 0; nf8 < 8; nf8++)
#pragma unroll
            for (int r = 0; r < 4; r++) {
                size_t idx = base + (size_t)(q0 + w * 32 + mf * 16 + g * 4 + r) * D
                             + nf8 * 16 + r16;
                Op[idx] = f2b(acc[mf][nf8][r] * inv[r]);
            }
    }
}

// ---------------------------------------------------------------- launch
extern "C" void kernel_launch(void* const* d_in, const int* in_sizes, int n_in,
                              void* d_out, int out_size, void* d_ws, size_t ws_size,
                              hipStream_t stream) {
    const float* x  = (const float*)d_in[0];
    const float* fc = (const float*)d_in[1];
    const float* fs = (const float*)d_in[2];
    const float* wq = (const float*)d_in[3];
    const float* wk = (const float*)d_in[4];
    const float* wv = (const float*)d_in[5];
    const float* wo = (const float*)d_in[6];
    float* out = (float*)d_out;

    const int S = 2048, D = 2048;
    const int M = 2 * S;              // 4096 rows
    const size_t MD = (size_t)M * D;  // 8,388,608
    const size_t DD = (size_t)D * D;  // 4,194,304

    u16* xb  = (u16*)d_ws;
    u16* wqb = xb  + MD;
    u16* wkb = wqb + DD;
    u16* wvb = wkb + DD;
    u16* wob = wvb + DD;
    u16* qb  = wob + DD;
    u16* kb  = qb  + MD;
    u16* vb  = kb  + MD;
    u16* ob  = vb  + MD;

    f2bf_kernel<<<(int)(MD / 1024), 256, 0, stream>>>(x,  xb,  (int)(MD / 4));
    f2bf_kernel<<<(int)(DD / 1024), 256, 0, stream>>>(wq, wqb, (int)(DD / 4));
    f2bf_kernel<<<(int)(DD / 1024), 256, 0, stream>>>(wk, wkb, (int)(DD / 4));
    f2bf_kernel<<<(int)(DD / 1024), 256, 0, stream>>>(wv, wvb, (int)(DD / 4));
    f2bf_kernel<<<(int)(DD / 1024), 256, 0, stream>>>(wo, wob, (int)(DD / 4));

    dim3 ggrid(D / 128, M / 128);  // (16, 32)
    gemm_bt<2><<<ggrid, 256, 0, stream>>>(xb, wqb, qb, M, D, D);   // Q pre-scaled
    gemm_bt<1><<<ggrid, 256, 0, stream>>>(xb, wkb, kb, M, D, D);
    gemm_bt<1><<<ggrid, 256, 0, stream>>>(xb, wvb, vb, M, D, D);

    rope_kernel<<<(int)(MD / 2 / 256), 256, 0, stream>>>(qb, kb, fc, fs);

    flash_attn<<<dim3(S / 256, 32), 512, 0, stream>>>(qb, kb, vb, ob);

    gemm_bt<0><<<ggrid, 256, 0, stream>>>(ob, wob, out, M, D, D);
}

// Round 5
// 304.273 us; speedup vs baseline: 1.5808x; 1.3487x over previous
//
#include <hip/hip_runtime.h>
#include <hip/hip_bf16.h>
#include <stdint.h>

typedef unsigned short u16;
typedef unsigned int   u32;

typedef __attribute__((ext_vector_type(8))) short bf16x8;   // 8 bf16 (4 VGPRs)
typedef __attribute__((ext_vector_type(4))) float f32x4;
typedef __attribute__((ext_vector_type(4))) float f4;
typedef __attribute__((ext_vector_type(4))) u16   u16x4;

#define GLOBAL_AS __attribute__((address_space(1)))
#define LDS_AS    __attribute__((address_space(3)))

// 1/sqrt(128) * log2(e)  -- folded into Q so softmax exp is bare v_exp_f32
#define QSCALE (0.088388347648318447f * 1.4426950408889634f)

__device__ __forceinline__ void gload_lds16(const void* gsrc, void* ldst) {
    __builtin_amdgcn_global_load_lds((GLOBAL_AS const u32*)gsrc,
                                     (LDS_AS u32*)ldst, 16, 0, 0);
}

__device__ __forceinline__ float b2f(u16 u) {
    union { u32 i; float f; } x; x.i = ((u32)u) << 16; return x.f;
}
__device__ __forceinline__ u16 f2b(float f) {          // RNE
    u32 u = __builtin_bit_cast(u32, f);
    u = (u + 0x7fff + ((u >> 16) & 1)) >> 16;
    return (u16)u;
}
__device__ __forceinline__ u16 f2b_tr(float f) {       // truncate (P-weights only)
    return (u16)(__builtin_bit_cast(u32, f) >> 16);
}

// ---------------------------------------------------------------- converts
__global__ __launch_bounds__(256) void f2bf_kernel(const float* __restrict__ in,
                                                   u16* __restrict__ out, int n4) {
    int i = blockIdx.x * blockDim.x + threadIdx.x;
    if (i >= n4) return;
    f4 v = ((const f4*)in)[i];
    u16x4 o;
    o[0] = f2b(v[0]); o[1] = f2b(v[1]); o[2] = f2b(v[2]); o[3] = f2b(v[3]);
    ((u16x4*)out)[i] = o;
}

// ---------------------------------------------------------------- RoPE on merged QKV
// qkv rows stride 6144: [Q(2048) | K(2048) | V(2048)]; rotate Q and K planes.
__global__ __launch_bounds__(256) void rope_kernel(u16* __restrict__ qkv,
                                                   const float* __restrict__ fc,
                                                   const float* __restrict__ fs) {
    const int S = 2048;
    int idx = blockIdx.x * blockDim.x + threadIdx.x;  // pair index
    const int p   = idx & 1023;      // pair within row = h*64 + i
    const int row = idx >> 10;       // b*S + s
    const int s   = row & (S - 1);
    const int i   = p & 63;
    const float c = fc[s * 64 + i], sn = fs[s * 64 + i];
    u16* qa = qkv + (size_t)row * 6144 + p * 2;
    u16* ka = qa + 2048;
    u32 qq = *(const u32*)qa;
    float qr = b2f((u16)(qq & 0xffff)), qi = b2f((u16)(qq >> 16));
    u32 kk = *(const u32*)ka;
    float kr = b2f((u16)(kk & 0xffff)), ki = b2f((u16)(kk >> 16));
    u16 e0 = f2b(qr * c - qi * sn), e1 = f2b(qr * sn + qi * c);
    *(u32*)qa = (u32)e0 | ((u32)e1 << 16);
    e0 = f2b(kr * c - ki * sn); e1 = f2b(kr * sn + ki * c);
    *(u32*)ka = (u32)e0 | ((u32)e1 << 16);
}

// ---------------------------------------------------------------- GEMM  C = A * B^T
// A: MxK bf16 rm, B: NxK bf16 rm, C: MxN. 128x128 tile, BK=64, 4 waves,
// LDS XOR-swizzled (row&7)<<4 via pre-swizzled gload source, XCD-swizzled grid.
// Swizzle involution (rule #21): store LDS[row][c]=G[row][c^msk], read col=(want^msk),
// msk=(row&7)<<4 over the FULL 7-bit byte column (bug in r4 applied it to bits 4-5 only).
// OUT_MODE: 0 = f32, 1 = bf16, 2 = bf16 with cols<2048 scaled by QSCALE (merged QKV)
template<int OUT_MODE>
__global__ __launch_bounds__(256)
void gemm_bt(const u16* __restrict__ A, const u16* __restrict__ B,
             void* __restrict__ Cptr, int M, int N, int Kdim) {
    __shared__ u16 ldsA[128 * 64];
    __shared__ u16 ldsB[128 * 64];
    const int t = threadIdx.x, l = t & 63, w = t >> 6;
    const int g = l >> 4, r16 = l & 15;

    // bijective XCD swizzle (nwg % 8 == 0 for all our launches)
    const int nwg = gridDim.x * gridDim.y;
    const int id  = blockIdx.y * gridDim.x + blockIdx.x;
    const int swz = (id & 7) * (nwg >> 3) + (id >> 3);
    const int bx  = swz % gridDim.x, by = swz / gridDim.x;
    const int m0 = by * 128, n0 = bx * 128;
    const int wr = (w >> 1) * 64, wc = (w & 1) * 64;

    f32x4 acc[4][4];
#pragma unroll
    for (int i = 0; i < 4; i++)
#pragma unroll
        for (int j = 0; j < 4; j++) acc[i][j] = (f32x4){0.f, 0.f, 0.f, 0.f};

    // staging: 4 instrs each for A,B; dest byte o = q*4096 + w*1024 + l*16
    // LDS[row][c] = G[row][c ^ ((row&7)<<4)]  (c = byte col in [0,128))
    const u16* ap[4]; const u16* bp[4];
#pragma unroll
    for (int q = 0; q < 4; q++) {
        const int o = q * 4096 + w * 1024 + l * 16;
        const int row = o >> 7;
        const int cb = (o & 127) ^ ((row & 7) << 4);
        ap[q] = A + (size_t)(m0 + row) * Kdim + (cb >> 1);
        bp[q] = B + (size_t)(n0 + row) * Kdim + (cb >> 1);
    }

    for (int k0 = 0; k0 < Kdim; k0 += 64) {
        __syncthreads();
#pragma unroll
        for (int q = 0; q < 4; q++) {
            gload_lds16(ap[q], (char*)ldsA + q * 4096 + w * 1024);
            gload_lds16(bp[q], (char*)ldsB + q * 4096 + w * 1024);
            ap[q] += 64; bp[q] += 64;
        }
        __syncthreads();
#pragma unroll
        for (int kk = 0; kk < 2; kk++) {
            bf16x8 af[4], bfr[4];
            // FIX: XOR over full column (incl. bit 6) keeps cb < 128, in-row
            const int cb = (kk * 64 + g * 16) ^ ((r16 & 7) << 4);
#pragma unroll
            for (int i = 0; i < 4; i++) {
                af[i]  = *(const bf16x8*)((const char*)ldsA + (wr + i * 16 + r16) * 128 + cb);
                bfr[i] = *(const bf16x8*)((const char*)ldsB + (wc + i * 16 + r16) * 128 + cb);
            }
#pragma unroll
            for (int mi = 0; mi < 4; mi++)
#pragma unroll
                for (int ni = 0; ni < 4; ni++)
                    acc[mi][ni] = __builtin_amdgcn_mfma_f32_16x16x32_bf16(af[mi], bfr[ni],
                                                                          acc[mi][ni], 0, 0, 0);
        }
    }

#pragma unroll
    for (int mi = 0; mi < 4; mi++)
#pragma unroll
        for (int ni = 0; ni < 4; ni++)
#pragma unroll
            for (int r = 0; r < 4; r++) {
                int row = m0 + wr + mi * 16 + g * 4 + r;
                int col = n0 + wc + ni * 16 + r16;
                float v = acc[mi][ni][r];
                if (OUT_MODE == 0)      ((float*)Cptr)[(size_t)row * N + col] = v;
                else if (OUT_MODE == 1) ((u16*)Cptr)[(size_t)row * N + col] = f2b(v);
                else ((u16*)Cptr)[(size_t)row * N + col] =
                         f2b(col < 2048 ? v * QSCALE : v);
            }
}

// ---------------------------------------------------------------- causal flash attention v4
// QBLK=128 (8 waves x 16 rows), KVBLK=128. Each block runs TWO q-tiles
// sequentially: tq = by and 15-by  -> every block = exactly 17 kv-iterations.
// grid (32 bh, 8) -> XCD = bh%8 (K/V panels L2-pinned: 4 bh x 1MB = 4MB/XCD).
// K double-buffered (gload_lds, XOR-swizzled); V^T reg-staged issue-early/write-late.
// Q pre-scaled by 1/sqrt(hd)*log2e; softmax = bare exp2; P stored truncated.
__global__ __launch_bounds__(512, 2)
void flash_attn(const u16* __restrict__ QKV, u16* __restrict__ Op) {
    const int S = 2048, DQ = 6144, DO = 2048;
    __shared__ u16 klds[2][128 * 128];    // swizzled byte^=((row&7)<<4)
    __shared__ u16 vtlds[128 * 136];      // V^T [d][kv], kv padded 128->136
    __shared__ u16 plds[8][16 * 136];     // per-wave P
    const int t = threadIdx.x, l = t & 63, w = t >> 6;   // w 0..7
    const int g = l >> 4, r16 = l & 15;
    const int bh = blockIdx.x, b = bh >> 4, h = bh & 15;
    const size_t base = ((size_t)(b * S)) * DQ + h * 128;
    const u16* qp = QKV + base;
    const u16* kp = qp + 2048;
    const u16* vp = qp + 4096;
    const size_t obase = ((size_t)(b * S)) * DO + h * 128;

    for (int task = 0; task < 2; ++task) {
        const int tq = task ? (15 - (int)blockIdx.y) : (int)blockIdx.y;
        const int q0 = tq * 128;
        const int nkt = tq + 1;

        bf16x8 qf[4];
#pragma unroll
        for (int ks = 0; ks < 4; ks++)
            qf[ks] = *(const bf16x8*)(qp + (size_t)(q0 + w * 16 + r16) * DQ
                                      + ks * 32 + g * 8);

        f32x4 acc[8];
#pragma unroll
        for (int i = 0; i < 8; i++) acc[i] = (f32x4){0.f, 0.f, 0.f, 0.f};
        float m_run[4], s_run[4];
#pragma unroll
        for (int r = 0; r < 4; r++) { m_run[r] = -3.0e38f; s_run[r] = 0.f; }

        auto stageK = [&](int bi, int kv0) {
#pragma unroll
            for (int i = 0; i < 4; i++) {
                const int o = (w * 4 + i) * 1024 + l * 16;
                const int row = o >> 8;
                const int cb = (o & 255) ^ ((row & 7) << 4);
                gload_lds16(kp + (size_t)(kv0 + row) * DQ + (cb >> 1),
                            (char*)klds[bi] + (w * 4 + i) * 1024);
            }
        };
        bf16x8 vv[2][2];
        auto loadV = [&](int kv0) {
#pragma unroll
            for (int c = 0; c < 2; c++)
#pragma unroll
                for (int kh = 0; kh < 2; kh++)
                    vv[c][kh] = *(const bf16x8*)(vp + (size_t)(kv0 + kh * 64 + l) * DQ
                                                 + (w * 16 + c * 8));
        };
        auto writeVT = [&]() {
#pragma unroll
            for (int c = 0; c < 2; c++)
#pragma unroll
                for (int kh = 0; kh < 2; kh++) {
                    const int d0 = w * 16 + c * 8;
#pragma unroll
                    for (int j = 0; j < 8; j++)
                        vtlds[(d0 + j) * 136 + kh * 64 + l] = (u16)vv[c][kh][j];
                }
        };

        stageK(0, 0);
        loadV(0);
        __syncthreads();
        writeVT();
        __syncthreads();

        int cur = 0;
        for (int kt = 0; kt < nkt; ++kt) {
            const int kv0 = kt * 128;
            const bool more = (kt + 1 < nkt);
            if (more) { stageK(cur ^ 1, kv0 + 128); loadV(kv0 + 128); }

            // ---- QK^T
            f32x4 sf[8];
#pragma unroll
            for (int nf = 0; nf < 8; nf++) sf[nf] = (f32x4){0.f, 0.f, 0.f, 0.f};
#pragma unroll
            for (int nf = 0; nf < 8; nf++) {
                const int row = nf * 16 + r16;
                const int rb = row * 256;
#pragma unroll
                for (int ks = 0; ks < 4; ks++) {
                    const int cb = (ks * 64 + g * 16) ^ ((row & 7) << 4);
                    bf16x8 kf = *(const bf16x8*)((const char*)klds[cur] + rb + cb);
                    sf[nf] = __builtin_amdgcn_mfma_f32_16x16x32_bf16(qf[ks], kf,
                                                                     sf[nf], 0, 0, 0);
                }
            }

            const bool diag = (kt == tq);
            float mt[4];
#pragma unroll
            for (int r = 0; r < 4; r++) mt[r] = -3.0e38f;
#pragma unroll
            for (int nf = 0; nf < 8; nf++)
#pragma unroll
                for (int r = 0; r < 4; r++) {
                    float s = sf[nf][r];
                    if (diag) {
                        int qrow = q0 + w * 16 + g * 4 + r;
                        int kcol = kv0 + nf * 16 + r16;
                        if (kcol > qrow) s = -3.0e38f;
                    }
                    sf[nf][r] = s;
                    mt[r] = fmaxf(mt[r], s);
                }
#pragma unroll
            for (int r = 0; r < 4; r++) {
#pragma unroll
                for (int d = 1; d < 16; d <<= 1)
                    mt[r] = fmaxf(mt[r], __shfl_xor(mt[r], d));
            }
            // defer-max (T13): rescale only if some row max grew > 8 (log2 domain)
            int grow = (mt[0] > m_run[0] + 8.f) | (mt[1] > m_run[1] + 8.f) |
                       (mt[2] > m_run[2] + 8.f) | (mt[3] > m_run[3] + 8.f);
            if (__any(grow)) {
#pragma unroll
                for (int r = 0; r < 4; r++) {
                    float mn = fmaxf(m_run[r], mt[r]);
                    float alpha = exp2f(m_run[r] - mn);
                    m_run[r] = mn;
                    s_run[r] *= alpha;
#pragma unroll
                    for (int i = 0; i < 8; i++) acc[i][r] *= alpha;
                }
            }
            float psum[4];
#pragma unroll
            for (int r = 0; r < 4; r++) psum[r] = 0.f;
#pragma unroll
            for (int nf = 0; nf < 8; nf++)
#pragma unroll
                for (int r = 0; r < 4; r++) {
                    float p = exp2f(sf[nf][r] - m_run[r]);
                    psum[r] += p;
                    plds[w][(g * 4 + r) * 136 + nf * 16 + r16] = f2b_tr(p);
                }
#pragma unroll
            for (int r = 0; r < 4; r++) {
#pragma unroll
                for (int d = 1; d < 16; d <<= 1)
                    psum[r] += __shfl_xor(psum[r], d);
                s_run[r] += psum[r];
            }
            // ---- PV
            __builtin_amdgcn_s_setprio(1);
#pragma unroll
            for (int ks2 = 0; ks2 < 4; ks2++) {
                bf16x8 pf = *(const bf16x8*)(&plds[w][r16 * 136 + ks2 * 32 + g * 8]);
#pragma unroll
                for (int nf8 = 0; nf8 < 8; nf8++) {
                    bf16x8 vf = *(const bf16x8*)(&vtlds[(nf8 * 16 + r16) * 136
                                                         + ks2 * 32 + g * 8]);
                    acc[nf8] = __builtin_amdgcn_mfma_f32_16x16x32_bf16(pf, vf,
                                                                       acc[nf8], 0, 0, 0);
                }
            }
            __builtin_amdgcn_s_setprio(0);

            __syncthreads();
            if (more) writeVT();
            __syncthreads();
            cur ^= 1;
        }

        float inv[4];
#pragma unroll
        for (int r = 0; r < 4; r++) inv[r] = 1.0f / s_run[r];
#pragma unroll
        for (int nf8 = 0; nf8 < 8; nf8++)
#pragma unroll
            for (int r = 0; r < 4; r++) {
                size_t idx = obase + (size_t)(q0 + w * 16 + g * 4 + r) * DO
                             + nf8 * 16 + r16;
                Op[idx] = f2b(acc[nf8][r] * inv[r]);
            }
    }
}

// ---------------------------------------------------------------- launch
extern "C" void kernel_launch(void* const* d_in, const int* in_sizes, int n_in,
                              void* d_out, int out_size, void* d_ws, size_t ws_size,
                              hipStream_t stream) {
    const float* x  = (const float*)d_in[0];
    const float* fc = (const float*)d_in[1];
    const float* fs = (const float*)d_in[2];
    const float* wq = (const float*)d_in[3];
    const float* wk = (const float*)d_in[4];
    const float* wv = (const float*)d_in[5];
    const float* wo = (const float*)d_in[6];
    float* out = (float*)d_out;

    const int S = 2048, D = 2048;
    const int M = 2 * S;              // 4096 rows
    const size_t MD = (size_t)M * D;  // 8,388,608
    const size_t DD = (size_t)D * D;  // 4,194,304

    u16* xb   = (u16*)d_ws;           // x bf16; later reused as flash output O
    u16* wqb  = xb  + MD;             // merged weight rows: [wq | wk | wv] = 6144 x 2048
    u16* wkb  = wqb + DD;
    u16* wvb  = wkb + DD;
    u16* wob  = wvb + DD;
    u16* qkvb = wob + DD;             // [4096][6144]

    f2bf_kernel<<<(int)(MD / 1024), 256, 0, stream>>>(x,  xb,  (int)(MD / 4));
    f2bf_kernel<<<(int)(DD / 1024), 256, 0, stream>>>(wq, wqb, (int)(DD / 4));
    f2bf_kernel<<<(int)(DD / 1024), 256, 0, stream>>>(wk, wkb, (int)(DD / 4));
    f2bf_kernel<<<(int)(DD / 1024), 256, 0, stream>>>(wv, wvb, (int)(DD / 4));
    f2bf_kernel<<<(int)(DD / 1024), 256, 0, stream>>>(wo, wob, (int)(DD / 4));

    // merged QKV projection: [4096][6144] = xb @ [6144 x 2048]^T, Q-cols pre-scaled
    gemm_bt<2><<<dim3(6144 / 128, M / 128), 256, 0, stream>>>(xb, wqb, qkvb, M, 6144, D);

    rope_kernel<<<(int)(MD / 2 / 256), 256, 0, stream>>>(qkvb, fc, fs);

    flash_attn<<<dim3(32, 8), 512, 0, stream>>>(qkvb, xb);   // O -> xb

    gemm_bt<0><<<dim3(D / 128, M / 128), 256, 0, stream>>>(xb, wob, out, M, D, D);
}

// Round 6
// 285.862 us; speedup vs baseline: 1.6826x; 1.0644x over previous
//
#include <hip/hip_runtime.h>
#include <hip/hip_bf16.h>
#include <stdint.h>

typedef unsigned short u16;
typedef unsigned int   u32;

typedef __attribute__((ext_vector_type(8))) short bf16x8;   // 8 bf16 (4 VGPRs)
typedef __attribute__((ext_vector_type(4))) float f32x4;
typedef __attribute__((ext_vector_type(4))) float f4;
typedef __attribute__((ext_vector_type(4))) u16   u16x4;

#define GLOBAL_AS __attribute__((address_space(1)))
#define LDS_AS    __attribute__((address_space(3)))

// 1/sqrt(128) * log2(e)  -- folded into Q so softmax exp is bare v_exp_f32
#define QSCALE (0.088388347648318447f * 1.4426950408889634f)

__device__ __forceinline__ void gload_lds16(const void* gsrc, void* ldst) {
    __builtin_amdgcn_global_load_lds((GLOBAL_AS const u32*)gsrc,
                                     (LDS_AS u32*)ldst, 16, 0, 0);
}

__device__ __forceinline__ float b2f(u16 u) {
    union { u32 i; float f; } x; x.i = ((u32)u) << 16; return x.f;
}
__device__ __forceinline__ u16 f2b(float f) {          // RNE
    u32 u = __builtin_bit_cast(u32, f);
    u = (u + 0x7fff + ((u >> 16) & 1)) >> 16;
    return (u16)u;
}
__device__ __forceinline__ u16 f2b_tr(float f) {       // truncate (P-weights only)
    return (u16)(__builtin_bit_cast(u32, f) >> 16);
}

// ---------------------------------------------------------------- converts
__global__ __launch_bounds__(256) void f2bf_kernel(const float* __restrict__ in,
                                                   u16* __restrict__ out, int n4) {
    int i = blockIdx.x * blockDim.x + threadIdx.x;
    if (i >= n4) return;
    f4 v = ((const f4*)in)[i];
    u16x4 o;
    o[0] = f2b(v[0]); o[1] = f2b(v[1]); o[2] = f2b(v[2]); o[3] = f2b(v[3]);
    ((u16x4*)out)[i] = o;
}

// ---------------------------------------------------------------- RoPE on merged QKV
// qkv rows stride 6144: [Q(2048) | K(2048) | V(2048)]; rotate Q and K planes.
__global__ __launch_bounds__(256) void rope_kernel(u16* __restrict__ qkv,
                                                   const float* __restrict__ fc,
                                                   const float* __restrict__ fs) {
    const int S = 2048;
    int idx = blockIdx.x * blockDim.x + threadIdx.x;  // pair index
    const int p   = idx & 1023;      // pair within row = h*64 + i
    const int row = idx >> 10;       // b*S + s
    const int s   = row & (S - 1);
    const int i   = p & 63;
    const float c = fc[s * 64 + i], sn = fs[s * 64 + i];
    u16* qa = qkv + (size_t)row * 6144 + p * 2;
    u16* ka = qa + 2048;
    u32 qq = *(const u32*)qa;
    float qr = b2f((u16)(qq & 0xffff)), qi = b2f((u16)(qq >> 16));
    u32 kk = *(const u32*)ka;
    float kr = b2f((u16)(kk & 0xffff)), ki = b2f((u16)(kk >> 16));
    u16 e0 = f2b(qr * c - qi * sn), e1 = f2b(qr * sn + qi * c);
    *(u32*)qa = (u32)e0 | ((u32)e1 << 16);
    e0 = f2b(kr * c - ki * sn); e1 = f2b(kr * sn + ki * c);
    *(u32*)ka = (u32)e0 | ((u32)e1 << 16);
}

// ---------------------------------------------------------------- GEMM  C = A * B^T
// v6: ring-3 counted-vmcnt pipeline (T4). BM=256, BN=128, BK=64, 8 waves (4Mx2N,
// 64x64 out each). LDS = 3 x 48KB K-tile buffers (A 32KB + B 16KB), XOR-swizzle
// (row&7)<<4 on both sides (store via pre-swizzled gload source, read via XOR).
// Per tile: barrier A -> stage t+2 (6 gloads) -> vmcnt(12) (t+1,t+2 in flight,
// NEVER 0) -> barrier B -> 16 ds_read_b128 -> 32 MFMA. Prefetch slack = 2 tiles.
// OUT_MODE: 0 = f32, 1 = bf16, 2 = bf16 with cols<2048 scaled by QSCALE
template<int OUT_MODE>
__global__ __launch_bounds__(512, 2)
void gemm_bt(const u16* __restrict__ A, const u16* __restrict__ B,
             void* __restrict__ Cptr, int M, int N, int Kdim) {
    __shared__ char lds[3][49152];          // 144KB: [buf][A 32KB | B 16KB]
    const int t = threadIdx.x, l = t & 63, w = t >> 6;   // 8 waves
    const int g = l >> 4, r16 = l & 15;

    // bijective XCD swizzle (nwg % 8 == 0 for all our launches)
    const int nwg = gridDim.x * gridDim.y;
    const int id  = blockIdx.y * gridDim.x + blockIdx.x;
    const int swz = (id & 7) * (nwg >> 3) + (id >> 3);
    const int bx  = swz % gridDim.x, by = swz / gridDim.x;
    const int m0 = by * 256, n0 = bx * 128;
    const int wm = w >> 1, wn = w & 1;      // wave grid 4M x 2N
    const int rA = wm * 64, rB = wn * 64;

    f32x4 acc[4][4];
#pragma unroll
    for (int i = 0; i < 4; i++)
#pragma unroll
        for (int j = 0; j < 4; j++) acc[i][j] = (f32x4){0.f, 0.f, 0.f, 0.f};

    const int nk = Kdim >> 6;               // 32 K-tiles

    auto stage = [&](int kt, int bi) {
        const int k0 = kt << 6;
#pragma unroll
        for (int q = 0; q < 4; q++) {       // A half: 32KB
            const int o = q * 8192 + w * 1024 + l * 16;
            const int row = o >> 7;
            const int cb = (o & 127) ^ ((row & 7) << 4);
            gload_lds16(A + (size_t)(m0 + row) * Kdim + k0 + (cb >> 1),
                        &lds[bi][q * 8192 + w * 1024]);
        }
#pragma unroll
        for (int q = 0; q < 2; q++) {       // B half: 16KB at +32768
            const int o = q * 8192 + w * 1024 + l * 16;
            const int row = o >> 7;
            const int cb = (o & 127) ^ ((row & 7) << 4);
            gload_lds16(B + (size_t)(n0 + row) * Kdim + k0 + (cb >> 1),
                        &lds[bi][32768 + q * 8192 + w * 1024]);
        }
    };

    stage(0, 0);
    stage(1, 1);

    for (int kt = 0; kt < nk; ++kt) {
        const int cur = kt % 3;
        __builtin_amdgcn_sched_barrier(0);
        __builtin_amdgcn_s_barrier();                    // [A] prev reads of target buf done
        stage((kt + 2) % nk, (kt + 2) % 3);              // wrap: tail reloads are discarded
        asm volatile("s_waitcnt vmcnt(12)" ::: "memory"); // tile kt landed; 12 younger in flight
        __builtin_amdgcn_s_barrier();                    // [B] tile kt visible to all waves
        __builtin_amdgcn_sched_barrier(0);

        const char* Ab = lds[cur];
        const char* Bb = lds[cur] + 32768;
        bf16x8 af[2][4], bfr[2][4];
#pragma unroll
        for (int kk = 0; kk < 2; kk++)
#pragma unroll
            for (int i = 0; i < 4; i++) {
                const int rowa = rA + i * 16 + r16;
                const int cba = (kk * 64 + g * 16) ^ ((rowa & 7) << 4);
                af[kk][i] = *(const bf16x8*)(Ab + rowa * 128 + cba);
                const int rowb = rB + i * 16 + r16;
                const int cbb = (kk * 64 + g * 16) ^ ((rowb & 7) << 4);
                bfr[kk][i] = *(const bf16x8*)(Bb + rowb * 128 + cbb);
            }
#pragma unroll
        for (int kk = 0; kk < 2; kk++)
#pragma unroll
            for (int mi = 0; mi < 4; mi++)
#pragma unroll
                for (int ni = 0; ni < 4; ni++)
                    acc[mi][ni] = __builtin_amdgcn_mfma_f32_16x16x32_bf16(af[kk][mi],
                                                                          bfr[kk][ni],
                                                                          acc[mi][ni], 0, 0, 0);
    }

#pragma unroll
    for (int mi = 0; mi < 4; mi++)
#pragma unroll
        for (int ni = 0; ni < 4; ni++)
#pragma unroll
            for (int r = 0; r < 4; r++) {
                int row = m0 + rA + mi * 16 + g * 4 + r;
                int col = n0 + rB + ni * 16 + r16;
                float v = acc[mi][ni][r];
                if (OUT_MODE == 0)      ((float*)Cptr)[(size_t)row * N + col] = v;
                else if (OUT_MODE == 1) ((u16*)Cptr)[(size_t)row * N + col] = f2b(v);
                else ((u16*)Cptr)[(size_t)row * N + col] =
                         f2b(col < 2048 ? v * QSCALE : v);
            }
}

// ---------------------------------------------------------------- causal flash attention v4
// QBLK=128 (8 waves x 16 rows), KVBLK=128. Each block runs TWO q-tiles
// sequentially: tq = by and 15-by  -> every block = exactly 17 kv-iterations.
// grid (32 bh, 8) -> XCD = bh%8 (K/V panels L2-pinned: 4 bh x 1MB = 4MB/XCD).
// K double-buffered (gload_lds, XOR-swizzled); V^T reg-staged issue-early/write-late.
// Q pre-scaled by 1/sqrt(hd)*log2e; softmax = bare exp2; P stored truncated.
__global__ __launch_bounds__(512, 2)
void flash_attn(const u16* __restrict__ QKV, u16* __restrict__ Op) {
    const int S = 2048, DQ = 6144, DO = 2048;
    __shared__ u16 klds[2][128 * 128];    // swizzled byte^=((row&7)<<4)
    __shared__ u16 vtlds[128 * 136];      // V^T [d][kv], kv padded 128->136
    __shared__ u16 plds[8][16 * 136];     // per-wave P
    const int t = threadIdx.x, l = t & 63, w = t >> 6;   // w 0..7
    const int g = l >> 4, r16 = l & 15;
    const int bh = blockIdx.x, b = bh >> 4, h = bh & 15;
    const size_t base = ((size_t)(b * S)) * DQ + h * 128;
    const u16* qp = QKV + base;
    const u16* kp = qp + 2048;
    const u16* vp = qp + 4096;
    const size_t obase = ((size_t)(b * S)) * DO + h * 128;

    for (int task = 0; task < 2; ++task) {
        const int tq = task ? (15 - (int)blockIdx.y) : (int)blockIdx.y;
        const int q0 = tq * 128;
        const int nkt = tq + 1;

        bf16x8 qf[4];
#pragma unroll
        for (int ks = 0; ks < 4; ks++)
            qf[ks] = *(const bf16x8*)(qp + (size_t)(q0 + w * 16 + r16) * DQ
                                      + ks * 32 + g * 8);

        f32x4 acc[8];
#pragma unroll
        for (int i = 0; i < 8; i++) acc[i] = (f32x4){0.f, 0.f, 0.f, 0.f};
        float m_run[4], s_run[4];
#pragma unroll
        for (int r = 0; r < 4; r++) { m_run[r] = -3.0e38f; s_run[r] = 0.f; }

        auto stageK = [&](int bi, int kv0) {
#pragma unroll
            for (int i = 0; i < 4; i++) {
                const int o = (w * 4 + i) * 1024 + l * 16;
                const int row = o >> 8;
                const int cb = (o & 255) ^ ((row & 7) << 4);
                gload_lds16(kp + (size_t)(kv0 + row) * DQ + (cb >> 1),
                            (char*)klds[bi] + (w * 4 + i) * 1024);
            }
        };
        bf16x8 vv[2][2];
        auto loadV = [&](int kv0) {
#pragma unroll
            for (int c = 0; c < 2; c++)
#pragma unroll
                for (int kh = 0; kh < 2; kh++)
                    vv[c][kh] = *(const bf16x8*)(vp + (size_t)(kv0 + kh * 64 + l) * DQ
                                                 + (w * 16 + c * 8));
        };
        auto writeVT = [&]() {
#pragma unroll
            for (int c = 0; c < 2; c++)
#pragma unroll
                for (int kh = 0; kh < 2; kh++) {
                    const int d0 = w * 16 + c * 8;
#pragma unroll
                    for (int j = 0; j < 8; j++)
                        vtlds[(d0 + j) * 136 + kh * 64 + l] = (u16)vv[c][kh][j];
                }
        };

        stageK(0, 0);
        loadV(0);
        __syncthreads();
        writeVT();
        __syncthreads();

        int cur = 0;
        for (int kt = 0; kt < nkt; ++kt) {
            const int kv0 = kt * 128;
            const bool more = (kt + 1 < nkt);
            if (more) { stageK(cur ^ 1, kv0 + 128); loadV(kv0 + 128); }

            // ---- QK^T
            f32x4 sf[8];
#pragma unroll
            for (int nf = 0; nf < 8; nf++) sf[nf] = (f32x4){0.f, 0.f, 0.f, 0.f};
#pragma unroll
            for (int nf = 0; nf < 8; nf++) {
                const int row = nf * 16 + r16;
                const int rb = row * 256;
#pragma unroll
                for (int ks = 0; ks < 4; ks++) {
                    const int cb = (ks * 64 + g * 16) ^ ((row & 7) << 4);
                    bf16x8 kf = *(const bf16x8*)((const char*)klds[cur] + rb + cb);
                    sf[nf] = __builtin_amdgcn_mfma_f32_16x16x32_bf16(qf[ks], kf,
                                                                     sf[nf], 0, 0, 0);
                }
            }

            const bool diag = (kt == tq);
            float mt[4];
#pragma unroll
            for (int r = 0; r < 4; r++) mt[r] = -3.0e38f;
#pragma unroll
            for (int nf = 0; nf < 8; nf++)
#pragma unroll
                for (int r = 0; r < 4; r++) {
                    float s = sf[nf][r];
                    if (diag) {
                        int qrow = q0 + w * 16 + g * 4 + r;
                        int kcol = kv0 + nf * 16 + r16;
                        if (kcol > qrow) s = -3.0e38f;
                    }
                    sf[nf][r] = s;
                    mt[r] = fmaxf(mt[r], s);
                }
#pragma unroll
            for (int r = 0; r < 4; r++) {
#pragma unroll
                for (int d = 1; d < 16; d <<= 1)
                    mt[r] = fmaxf(mt[r], __shfl_xor(mt[r], d));
            }
            // defer-max (T13): rescale only if some row max grew > 8 (log2 domain)
            int grow = (mt[0] > m_run[0] + 8.f) | (mt[1] > m_run[1] + 8.f) |
                       (mt[2] > m_run[2] + 8.f) | (mt[3] > m_run[3] + 8.f);
            if (__any(grow)) {
#pragma unroll
                for (int r = 0; r < 4; r++) {
                    float mn = fmaxf(m_run[r], mt[r]);
                    float alpha = exp2f(m_run[r] - mn);
                    m_run[r] = mn;
                    s_run[r] *= alpha;
#pragma unroll
                    for (int i = 0; i < 8; i++) acc[i][r] *= alpha;
                }
            }
            float psum[4];
#pragma unroll
            for (int r = 0; r < 4; r++) psum[r] = 0.f;
#pragma unroll
            for (int nf = 0; nf < 8; nf++)
#pragma unroll
                for (int r = 0; r < 4; r++) {
                    float p = exp2f(sf[nf][r] - m_run[r]);
                    psum[r] += p;
                    plds[w][(g * 4 + r) * 136 + nf * 16 + r16] = f2b_tr(p);
                }
#pragma unroll
            for (int r = 0; r < 4; r++) {
#pragma unroll
                for (int d = 1; d < 16; d <<= 1)
                    psum[r] += __shfl_xor(psum[r], d);
                s_run[r] += psum[r];
            }
            // ---- PV
            __builtin_amdgcn_s_setprio(1);
#pragma unroll
            for (int ks2 = 0; ks2 < 4; ks2++) {
                bf16x8 pf = *(const bf16x8*)(&plds[w][r16 * 136 + ks2 * 32 + g * 8]);
#pragma unroll
                for (int nf8 = 0; nf8 < 8; nf8++) {
                    bf16x8 vf = *(const bf16x8*)(&vtlds[(nf8 * 16 + r16) * 136
                                                         + ks2 * 32 + g * 8]);
                    acc[nf8] = __builtin_amdgcn_mfma_f32_16x16x32_bf16(pf, vf,
                                                                       acc[nf8], 0, 0, 0);
                }
            }
            __builtin_amdgcn_s_setprio(0);

            __syncthreads();
            if (more) writeVT();
            __syncthreads();
            cur ^= 1;
        }

        float inv[4];
#pragma unroll
        for (int r = 0; r < 4; r++) inv[r] = 1.0f / s_run[r];
#pragma unroll
        for (int nf8 = 0; nf8 < 8; nf8++)
#pragma unroll
            for (int r = 0; r < 4; r++) {
                size_t idx = obase + (size_t)(q0 + w * 16 + g * 4 + r) * DO
                             + nf8 * 16 + r16;
                Op[idx] = f2b(acc[nf8][r] * inv[r]);
            }
    }
}

// ---------------------------------------------------------------- launch
extern "C" void kernel_launch(void* const* d_in, const int* in_sizes, int n_in,
                              void* d_out, int out_size, void* d_ws, size_t ws_size,
                              hipStream_t stream) {
    const float* x  = (const float*)d_in[0];
    const float* fc = (const float*)d_in[1];
    const float* fs = (const float*)d_in[2];
    const float* wq = (const float*)d_in[3];
    const float* wk = (const float*)d_in[4];
    const float* wv = (const float*)d_in[5];
    const float* wo = (const float*)d_in[6];
    float* out = (float*)d_out;

    const int S = 2048, D = 2048;
    const int M = 2 * S;              // 4096 rows
    const size_t MD = (size_t)M * D;  // 8,388,608
    const size_t DD = (size_t)D * D;  // 4,194,304

    u16* xb   = (u16*)d_ws;           // x bf16; later reused as flash output O
    u16* wqb  = xb  + MD;             // merged weight rows: [wq | wk | wv] = 6144 x 2048
    u16* wkb  = wqb + DD;
    u16* wvb  = wkb + DD;
    u16* wob  = wvb + DD;
    u16* qkvb = wob + DD;             // [4096][6144]

    f2bf_kernel<<<(int)(MD / 1024), 256, 0, stream>>>(x,  xb,  (int)(MD / 4));
    f2bf_kernel<<<(int)(DD / 1024), 256, 0, stream>>>(wq, wqb, (int)(DD / 4));
    f2bf_kernel<<<(int)(DD / 1024), 256, 0, stream>>>(wk, wkb, (int)(DD / 4));
    f2bf_kernel<<<(int)(DD / 1024), 256, 0, stream>>>(wv, wvb, (int)(DD / 4));
    f2bf_kernel<<<(int)(DD / 1024), 256, 0, stream>>>(wo, wob, (int)(DD / 4));

    // merged QKV projection: [4096][6144] = xb @ [6144 x 2048]^T, Q-cols pre-scaled
    gemm_bt<2><<<dim3(6144 / 128, M / 256), 512, 0, stream>>>(xb, wqb, qkvb, M, 6144, D);

    rope_kernel<<<(int)(MD / 2 / 256), 256, 0, stream>>>(qkvb, fc, fs);

    flash_attn<<<dim3(32, 8), 512, 0, stream>>>(qkvb, xb);   // O -> xb

    gemm_bt<0><<<dim3(D / 128, M / 256), 512, 0, stream>>>(xb, wob, out, M, D, D);
}